// Round 19
// baseline (143.506 us; speedup 1.0000x reference)
//
#include <hip/hip_runtime.h>

#define NN 50000
#define NNP 50048   // padded rows: 782 * 64
#define NE 640000
#define IC 128
#define HC 256
#define PAD 64      // padded CSR row capacity; P(deg>=64)~1e-25 for Poisson(12.8); guarded anyway

#define BUILD_BLOCKS  ((NE + 255) / 256)           // 2500
#define TOBF16_BLOCKS (NN * IC / 8 / 256)          // 3125 (32B per thread)
#define WPACK_BLOCKS  32
#define BP_BLOCKS     (BUILD_BLOCKS + TOBF16_BLOCKS + WPACK_BLOCKS)

typedef __attribute__((ext_vector_type(8))) short short8;
typedef __attribute__((ext_vector_type(4))) float f32x4;

__device__ __forceinline__ unsigned short f2bf(float f) {   // fp32 -> bf16 RNE
    unsigned int u = __float_as_uint(f);
    unsigned int r = u + 0x7FFFu + ((u >> 16) & 1u);
    return (unsigned short)(r >> 16);
}
__device__ __forceinline__ float bflo(unsigned int v) { return __uint_as_float(v << 16); }
__device__ __forceinline__ float bfhi(unsigned int v) { return __uint_as_float(v & 0xffff0000u); }

// ---------------- kernel 1: zero spread-degi (one counter per 64B line) ----------------
__global__ __launch_bounds__(256) void k_zero(int* __restrict__ degi) {
    int i = blockIdx.x * 256 + threadIdx.x;
    if (i < NN * 4) ((uint4*)degi)[i] = make_uint4(0u, 0u, 0u, 0u);   // NN*16 ints
}

// ---------------- kernel 2: CSR build ∥ x->bf16 ∥ W pack (independent block ranges) ----------------
__global__ __launch_bounds__(256) void k_bprep(const int* __restrict__ ei,
                                               const float* __restrict__ x,
                                               const float* __restrict__ Wl0,
                                               const float* __restrict__ Wr0,
                                               int* __restrict__ degi,
                                               unsigned short* __restrict__ csrp,
                                               unsigned short* __restrict__ Ax,
                                               unsigned short* __restrict__ Bp) {
    int b = blockIdx.x;
    int t = threadIdx.x;
    if (b < BUILD_BLOCKS) {
        // one-pass padded-CSR build; line-isolated counters
        int e = b * 256 + t;
        if (e < NE) {
            int src = ei[e];
            int dst = ei[NE + e];
            int rank = atomicAdd(&degi[dst << 4], 1);
            if (rank < PAD) csrp[dst * PAD + rank] = (unsigned short)src;
        }
    } else if (b < BUILD_BLOCKS + TOBF16_BLOCKS) {
        // x -> bf16 into compact Ax[NNP][128]
        int i = (b - BUILD_BLOCKS) * 256 + t;      // over NN*IC/8 8-float chunks
        int n = i >> 4;
        int c = (i & 15) * 8;
        float4 v0 = ((const float4*)x)[i * 2];
        float4 v1 = ((const float4*)x)[i * 2 + 1];
        ushort4 o0, o1;
        o0.x = f2bf(v0.x); o0.y = f2bf(v0.y); o0.z = f2bf(v0.z); o0.w = f2bf(v0.w);
        o1.x = f2bf(v1.x); o1.y = f2bf(v1.y); o1.z = f2bf(v1.z); o1.w = f2bf(v1.w);
        *(ushort4*)&Ax[(size_t)n * 128 + c] = o0;
        *(ushort4*)&Ax[(size_t)n * 128 + c + 4] = o1;
    } else {
        // pack [Wl0;Wr0] into MFMA B-fragment order:
        // Bp[kt(8)][nt(16)][lane(64)][e(8)], B[k][n]: k=kt*32+(lane>>4)*8+e, n=nt*16+(lane&15)
        int tt = (b - BUILD_BLOCKS - TOBF16_BLOCKS) * 256 + t;   // 8192 threads
        int l = tt & 63;
        int nt = (tt >> 6) & 15;
        int kt = tt >> 10;
        int n = nt * 16 + (l & 15);
        int kbase = kt * 32 + (l >> 4) * 8;
        unsigned short o[8];
        #pragma unroll
        for (int e = 0; e < 8; ++e) {
            int k = kbase + e;
            float w = (k < IC) ? Wl0[k * HC + n] : Wr0[(k - IC) * HC + n];
            o[e] = f2bf(w);
        }
        #pragma unroll
        for (int e = 0; e < 8; ++e) Bp[(size_t)tt * 8 + e] = o[e];
    }
}

// ---------------- kernel 3: fused gather-mean (block's own 64 nodes -> LDS) + MFMA GEMM ----------------
// H = relu([mean|x] @ [Wl0;Wr0] + bl0); g = H@Wl1; r = H@Wr1
// LDS: means 17,408 + Bs 32,768 = 50,176 B -> 3 blocks/CU; bounds(256,3) caps VGPR at ~170.
__global__ __launch_bounds__(256, 3) void k_aggemm(const int* __restrict__ degi,
                                                   const unsigned short* __restrict__ csrp,
                                                   const unsigned short* __restrict__ Ax,
                                                   const unsigned short* __restrict__ Bp,
                                                   const float* __restrict__ bl0,
                                                   const float* __restrict__ Wl1,
                                                   const float* __restrict__ Wr1,
                                                   float* __restrict__ g,
                                                   float* __restrict__ r) {
    __shared__ unsigned short means[64][136];   // pad 128->136: row stride 272B -> 2-way banks (free)
    __shared__ float4 Bs[2048];                 // 32 KB; epilogue tables overlay after last MFMA

    int t = threadIdx.x, w = t >> 6, l = t & 63;
    int nb = blockIdx.x * 64;

    // ---- phase A: gather-mean for this block's 64 nodes (wave w: nodes w*16..w*16+15)
    {
        int sg = l >> 3;       // 8 edge subgroups
        int s  = l & 7;        // uint4 slot: covers cols s*8.. and 64+s*8..
        const uint4* base = (const uint4*)Ax;   // 16 uint4 per 256B row
        for (int i = 0; i < 16; ++i) {
            int node = nb + w * 16 + i;
            int deg = (node < NN) ? min(degi[node << 4], PAD) : 0;
            int beg = node * PAD;
            float a[16];
            #pragma unroll
            for (int k = 0; k < 16; ++k) a[k] = 0.f;
            for (int j = sg; j < deg; j += 8) {
                int src = csrp[beg + j];
                uint4 v0 = base[(size_t)src * 16 + s];
                uint4 v1 = base[(size_t)src * 16 + 8 + s];
                a[0] += bflo(v0.x); a[1] += bfhi(v0.x);
                a[2] += bflo(v0.y); a[3] += bfhi(v0.y);
                a[4] += bflo(v0.z); a[5] += bfhi(v0.z);
                a[6] += bflo(v0.w); a[7] += bfhi(v0.w);
                a[8]  += bflo(v1.x); a[9]  += bfhi(v1.x);
                a[10] += bflo(v1.y); a[11] += bfhi(v1.y);
                a[12] += bflo(v1.z); a[13] += bfhi(v1.z);
                a[14] += bflo(v1.w); a[15] += bfhi(v1.w);
            }
            #pragma unroll
            for (int m = 8; m <= 32; m <<= 1)
                #pragma unroll
                for (int k = 0; k < 16; ++k) a[k] += __shfl_xor(a[k], m);
            if (sg == 0) {
                float inv = 1.0f / fmaxf((float)deg, 1.0f);
                uint4 o0, o1;
                o0.x = ((unsigned int)f2bf(a[1] * inv) << 16) | f2bf(a[0] * inv);
                o0.y = ((unsigned int)f2bf(a[3] * inv) << 16) | f2bf(a[2] * inv);
                o0.z = ((unsigned int)f2bf(a[5] * inv) << 16) | f2bf(a[4] * inv);
                o0.w = ((unsigned int)f2bf(a[7] * inv) << 16) | f2bf(a[6] * inv);
                o1.x = ((unsigned int)f2bf(a[9]  * inv) << 16) | f2bf(a[8]  * inv);
                o1.y = ((unsigned int)f2bf(a[11] * inv) << 16) | f2bf(a[10] * inv);
                o1.z = ((unsigned int)f2bf(a[13] * inv) << 16) | f2bf(a[12] * inv);
                o1.w = ((unsigned int)f2bf(a[15] * inv) << 16) | f2bf(a[14] * inv);
                *(uint4*)&means[w * 16 + i][s * 8] = o0;
                *(uint4*)&means[w * 16 + i][64 + s * 8] = o1;
            }
        }
    }
    __syncthreads();   // means ready

    // ---- phase B: MFMA (kt 0..3 A-frags from LDS means; kt 4..7 from global Ax)
    f32x4 acc[16];
    #pragma unroll
    for (int i = 0; i < 16; ++i) acc[i] = (f32x4){0.f, 0.f, 0.f, 0.f};

    const short8* Am  = (const short8*)&means[w * 16 + (l & 15)][(l >> 4) * 8];   // +kt*4 walks k
    const short8* A8x = (const short8*)Ax + ((size_t)(nb + w * 16 + (l & 15)) * 16 + (l >> 4));

    for (int q = 0; q < 4; ++q) {
        short8 af0, af1;
        if (q < 2) {                      // mean half (k 0..127): LDS
            af0 = Am[(q * 2 + 0) * 4];
            af1 = Am[(q * 2 + 1) * 4];
        } else {                          // x half (k 128..255): global, issued pre-barrier
            af0 = A8x[(q * 2 - 4) * 4];
            af1 = A8x[(q * 2 - 3) * 4];
        }
        __syncthreads();
        const float4* gsrc = (const float4*)(Bp + (size_t)q * 16384);  // 32KB quarter
        #pragma unroll
        for (int i = 0; i < 8; ++i)
            Bs[i * 256 + t] = gsrc[i * 256 + t];
        __syncthreads();
        const short8* B8 = (const short8*)Bs + l;
        #pragma unroll
        for (int nt = 0; nt < 16; ++nt) {
            short8 bf = B8[nt * 64];
            acc[nt] = __builtin_amdgcn_mfma_f32_16x16x32_bf16(af0, bf, acc[nt], 0, 0, 0);
        }
        B8 = (const short8*)Bs + (1024 + l);
        #pragma unroll
        for (int nt = 0; nt < 16; ++nt) {
            short8 bf = B8[nt * 64];
            acc[nt] = __builtin_amdgcn_mfma_f32_16x16x32_bf16(af1, bf, acc[nt], 0, 0, 0);
        }
    }

    // overlay epilogue tables into Bs (all waves done with B fragments)
    __syncthreads();
    float* tb = (float*)Bs;   // [0..767]=Wl1, [768..1535]=Wr1, [1536..1791]=bl0
    for (int i = t; i < HC * 3; i += 256) { tb[i] = Wl1[i]; tb[768 + i] = Wr1[i]; }
    tb[1536 + t] = bl0[t];
    __syncthreads();

    // epilogue: D lane l reg e = H[row=(l>>4)*4+e][col=nt*16+(l&15)]
    float pl[4][3] = {{0.f}}, pr[4][3] = {{0.f}};
    #pragma unroll
    for (int nt = 0; nt < 16; ++nt) {
        int col = nt * 16 + (l & 15);
        float bcol = tb[1536 + col];
        #pragma unroll
        for (int e = 0; e < 4; ++e) {
            float h = fmaxf(acc[nt][e] + bcol, 0.0f);
            #pragma unroll
            for (int j = 0; j < 3; ++j) {
                pl[e][j] = fmaf(h, tb[col * 3 + j], pl[e][j]);
                pr[e][j] = fmaf(h, tb[768 + col * 3 + j], pr[e][j]);
            }
        }
    }
    #pragma unroll
    for (int m = 1; m <= 8; m <<= 1) {
        #pragma unroll
        for (int e = 0; e < 4; ++e)
            #pragma unroll
            for (int j = 0; j < 3; ++j) {
                pl[e][j] += __shfl_xor(pl[e][j], m);
                pr[e][j] += __shfl_xor(pr[e][j], m);
            }
    }
    if ((l & 15) == 0) {
        #pragma unroll
        for (int e = 0; e < 4; ++e) {
            int node = nb + w * 16 + (l >> 4) * 4 + e;
            if (node < NN) {
                #pragma unroll
                for (int j = 0; j < 3; ++j) {
                    g[node * 3 + j] = pl[e][j];
                    r[node * 3 + j] = pr[e][j];
                }
            }
        }
    }
}

// ---------------- kernel 4: layer-1 gather + final output ----------------
__global__ __launch_bounds__(256) void k_out(const int* __restrict__ degi,
                                             const unsigned short* __restrict__ csrp,
                                             const float* __restrict__ g,
                                             const float* __restrict__ r,
                                             const float* __restrict__ bl1,
                                             float* __restrict__ out) {
    int tid = blockIdx.x * 256 + threadIdx.x;
    int n = tid >> 3;
    int sl = tid & 7;
    if (n >= NN) return;
    int deg = min(degi[n << 4], PAD);
    int beg = n * PAD;
    float s0 = 0.f, s1 = 0.f, s2 = 0.f;
    for (int j = sl; j < deg; j += 8) {
        int src = csrp[beg + j];
        s0 += g[src * 3 + 0];
        s1 += g[src * 3 + 1];
        s2 += g[src * 3 + 2];
    }
    #pragma unroll
    for (int m = 1; m < 8; m <<= 1) {
        s0 += __shfl_xor(s0, m);
        s1 += __shfl_xor(s1, m);
        s2 += __shfl_xor(s2, m);
    }
    if (sl == 0) {
        float inv = 1.0f / fmaxf((float)deg, 1.0f);
        out[n * 3 + 0] = s0 * inv + bl1[0] + r[n * 3 + 0];
        out[n * 3 + 1] = s1 * inv + bl1[1] + r[n * 3 + 1];
        out[n * 3 + 2] = s2 * inv + bl1[2] + r[n * 3 + 2];
    }
}

extern "C" void kernel_launch(void* const* d_in, const int* in_sizes, int n_in,
                              void* d_out, int out_size, void* d_ws, size_t ws_size,
                              hipStream_t stream) {
    const float* x   = (const float*)d_in[0];
    const int*   ei  = (const int*)d_in[1];
    const float* Wl0 = (const float*)d_in[2];
    const float* bl0 = (const float*)d_in[3];
    const float* Wr0 = (const float*)d_in[4];
    const float* Wl1 = (const float*)d_in[5];
    const float* bl1 = (const float*)d_in[6];
    const float* Wr1 = (const float*)d_in[7];
    float* out = (float*)d_out;

    char* ws = (char*)d_ws;
    int*            degi = (int*)(ws);                        //  3,200,064 (NN*16 ints)
    unsigned short* csrp = (unsigned short*)(ws + 3200064);   //  6,400,000 (NN*PAD*2)
    unsigned short* Ax   = (unsigned short*)(ws + 9600064);   // 12,812,288 (NNP*128*2)
    unsigned short* Bp   = (unsigned short*)(ws + 22412352);  //    131,072
    float*          g    = (float*)(ws + 22543424);           //    600,064
    float*          r    = (float*)(ws + 23143488);           //    600,064  -> ~23.7 MB

    k_zero  <<<(NN * 4 + 255) / 256, 256, 0, stream>>>(degi);
    k_bprep <<<BP_BLOCKS, 256, 0, stream>>>(ei, x, Wl0, Wr0, degi, csrp, Ax, Bp);
    k_aggemm<<<NNP / 64, 256, 0, stream>>>(degi, csrp, Ax, Bp, bl0, Wl1, Wr1, g, r);
    k_out   <<<(NN * 8 + 255) / 256, 256, 0, stream>>>(degi, csrp, g, r, bl1, out);
}

// Round 20
// 108.225 us; speedup vs baseline: 1.3260x; 1.3260x over previous
//
#include <hip/hip_runtime.h>

#define NN 50000
#define NNP 50048   // Ab rows padded to multiple of 64
#define NE 640000
#define IC 128
#define HC 256
#define PAD 64      // padded CSR row capacity; P(deg>=64)~1e-25 for Poisson(12.8); guarded anyway

#define BUILD_BLOCKS  ((NE + 255) / 256)           // 2500
#define TOBF16_BLOCKS (NN * IC / 8 / 256)          // 3125 (32B per thread)
#define WPACK_BLOCKS  32
#define BP_BLOCKS     (BUILD_BLOCKS + TOBF16_BLOCKS + WPACK_BLOCKS)

typedef __attribute__((ext_vector_type(8))) short short8;
typedef __attribute__((ext_vector_type(4))) float f32x4;

__device__ __forceinline__ unsigned short f2bf(float f) {   // fp32 -> bf16 RNE
    unsigned int u = __float_as_uint(f);
    unsigned int r = u + 0x7FFFu + ((u >> 16) & 1u);
    return (unsigned short)(r >> 16);
}
__device__ __forceinline__ float bflo(unsigned int v) { return __uint_as_float(v << 16); }
__device__ __forceinline__ float bfhi(unsigned int v) { return __uint_as_float(v & 0xffff0000u); }

// ---------------- kernel 1: zero spread-degi (one counter per 64B line) ----------------
__global__ __launch_bounds__(256) void k_zero(int* __restrict__ degi) {
    int i = blockIdx.x * 256 + threadIdx.x;
    if (i < NN * 4) ((uint4*)degi)[i] = make_uint4(0u, 0u, 0u, 0u);   // NN*16 ints
}

// ---------------- kernel 2: CSR build ∥ x->bf16 ∥ W pack (disjoint block ranges) ----------------
// build touches degi/csrp; tobf16 writes Ab right half; wpack writes Bp — independent,
// so prep work overlaps under the atomic pass instead of serializing before it.
__global__ __launch_bounds__(256) void k_bprep(const int* __restrict__ ei,
                                               const float* __restrict__ x,
                                               const float* __restrict__ Wl0,
                                               const float* __restrict__ Wr0,
                                               int* __restrict__ degi,
                                               unsigned short* __restrict__ csrp,
                                               unsigned short* __restrict__ Ab,
                                               unsigned short* __restrict__ Bp) {
    int b = blockIdx.x;
    int t = threadIdx.x;
    if (b < BUILD_BLOCKS) {
        int e = b * 256 + t;
        if (e < NE) {
            int src = ei[e];
            int dst = ei[NE + e];
            int rank = atomicAdd(&degi[dst << 4], 1);   // line-isolated counter
            if (rank < PAD) csrp[dst * PAD + rank] = (unsigned short)src;
        }
    } else if (b < BUILD_BLOCKS + TOBF16_BLOCKS) {
        // x -> bf16 into right half of Ab (Ab: ushort[NNP][256], cols 128..255 = x)
        int i = (b - BUILD_BLOCKS) * 256 + t;      // over NN*IC/8 8-float chunks
        int n = i >> 4;
        int c = (i & 15) * 8;
        float4 v0 = ((const float4*)x)[i * 2];
        float4 v1 = ((const float4*)x)[i * 2 + 1];
        ushort4 o0, o1;
        o0.x = f2bf(v0.x); o0.y = f2bf(v0.y); o0.z = f2bf(v0.z); o0.w = f2bf(v0.w);
        o1.x = f2bf(v1.x); o1.y = f2bf(v1.y); o1.z = f2bf(v1.z); o1.w = f2bf(v1.w);
        *(ushort4*)&Ab[(size_t)n * 256 + 128 + c] = o0;
        *(ushort4*)&Ab[(size_t)n * 256 + 128 + c + 4] = o1;
    } else {
        // pack [Wl0;Wr0] into MFMA B-fragment order:
        // Bp[kt(8)][nt(16)][lane(64)][e(8)], B[k][n]: k=kt*32+(lane>>4)*8+e, n=nt*16+(lane&15)
        int tt = (b - BUILD_BLOCKS - TOBF16_BLOCKS) * 256 + t;   // 8192 threads
        int l = tt & 63;
        int nt = (tt >> 6) & 15;
        int kt = tt >> 10;
        int n = nt * 16 + (l & 15);
        int kbase = kt * 32 + (l >> 4) * 8;
        unsigned short o[8];
        #pragma unroll
        for (int e = 0; e < 8; ++e) {
            int k = kbase + e;
            float w = (k < IC) ? Wl0[k * HC + n] : Wr0[(k - IC) * HC + n];
            o[e] = f2bf(w);
        }
        #pragma unroll
        for (int e = 0; e < 8; ++e) Bp[(size_t)tt * 8 + e] = o[e];
    }
}

// ---------------- kernel 3: gather-mean, wave per node (proven R15 form) ----------------
__global__ __launch_bounds__(256) void k_agg(const int* __restrict__ degi,
                                             const unsigned short* __restrict__ csrp,
                                             unsigned short* __restrict__ Ab) {
    int wid = (blockIdx.x * blockDim.x + threadIdx.x) >> 6;
    int lane = threadIdx.x & 63;
    if (wid >= NN) return;
    int deg = min(degi[wid << 4], PAD);
    int beg = wid * PAD;
    int sg = lane >> 3;        // 8 edge subgroups: 8 edges in flight per wave
    int s  = lane & 7;         // uint4 slots s and s+8 of the x-half
    const uint4* base = (const uint4*)Ab;     // 32 uint4 per 512B row

    float a[16];
    #pragma unroll
    for (int i = 0; i < 16; ++i) a[i] = 0.f;

    for (int j = sg; j < deg; j += 8) {
        int src = csrp[beg + j];
        uint4 v0 = base[(size_t)src * 32 + 16 + s];
        uint4 v1 = base[(size_t)src * 32 + 24 + s];
        a[0] += bflo(v0.x); a[1] += bfhi(v0.x);
        a[2] += bflo(v0.y); a[3] += bfhi(v0.y);
        a[4] += bflo(v0.z); a[5] += bfhi(v0.z);
        a[6] += bflo(v0.w); a[7] += bfhi(v0.w);
        a[8]  += bflo(v1.x); a[9]  += bfhi(v1.x);
        a[10] += bflo(v1.y); a[11] += bfhi(v1.y);
        a[12] += bflo(v1.z); a[13] += bfhi(v1.z);
        a[14] += bflo(v1.w); a[15] += bfhi(v1.w);
    }
    #pragma unroll
    for (int m = 8; m <= 32; m <<= 1)
        #pragma unroll
        for (int i = 0; i < 16; ++i) a[i] += __shfl_xor(a[i], m);

    if (sg == 0) {
        float inv = 1.0f / fmaxf((float)deg, 1.0f);
        uint4 o0, o1;
        o0.x = ((unsigned int)f2bf(a[1] * inv) << 16) | f2bf(a[0] * inv);
        o0.y = ((unsigned int)f2bf(a[3] * inv) << 16) | f2bf(a[2] * inv);
        o0.z = ((unsigned int)f2bf(a[5] * inv) << 16) | f2bf(a[4] * inv);
        o0.w = ((unsigned int)f2bf(a[7] * inv) << 16) | f2bf(a[6] * inv);
        o1.x = ((unsigned int)f2bf(a[9]  * inv) << 16) | f2bf(a[8]  * inv);
        o1.y = ((unsigned int)f2bf(a[11] * inv) << 16) | f2bf(a[10] * inv);
        o1.z = ((unsigned int)f2bf(a[13] * inv) << 16) | f2bf(a[12] * inv);
        o1.w = ((unsigned int)f2bf(a[15] * inv) << 16) | f2bf(a[14] * inv);
        ((uint4*)Ab)[(size_t)wid * 32 + s] = o0;
        ((uint4*)Ab)[(size_t)wid * 32 + 8 + s] = o1;
    }
}

// ---------------- kernel 4: MFMA GEMM (proven R15 v5) ----------------
// H = relu(Ab @ [Wl0;Wr0] + bl0); g = H@Wl1; r = H@Wr1
__global__ __launch_bounds__(256, 4) void k_gemm(const unsigned short* __restrict__ Ab,
                                                 const unsigned short* __restrict__ Bp,
                                                 const float* __restrict__ bl0,
                                                 const float* __restrict__ Wl1,
                                                 const float* __restrict__ Wr1,
                                                 float* __restrict__ g,
                                                 float* __restrict__ r) {
    __shared__ float4 Bs[2048];          // 32 KB: one K-quarter of packed B
    __shared__ float wl1s[HC][3];
    __shared__ float wr1s[HC][3];
    __shared__ float bls[HC];

    int t = threadIdx.x;
    for (int i = t; i < HC * 3; i += 256) {
        wl1s[i / 3][i % 3] = Wl1[i];
        wr1s[i / 3][i % 3] = Wr1[i];
    }
    for (int i = t; i < HC; i += 256) bls[i] = bl0[i];

    int w = t >> 6, l = t & 63;
    int n0 = blockIdx.x * 64 + w * 16;

    f32x4 acc[16];
    #pragma unroll
    for (int i = 0; i < 16; ++i) acc[i] = (f32x4){0.f, 0.f, 0.f, 0.f};

    // A-frag: lane l supplies A[n0 + (l&15)][kt*32 + (l>>4)*8 + e]
    const short8* A8 = (const short8*)Ab + ((size_t)(n0 + (l & 15)) * 32 + (l >> 4));

    for (int q = 0; q < 4; ++q) {
        // issue this quarter's two A fragments first: latency hides under stage+barrier
        short8 af0 = A8[(q * 2 + 0) * 4];
        short8 af1 = A8[(q * 2 + 1) * 4];
        __syncthreads();
        const float4* gsrc = (const float4*)(Bp + (size_t)q * 16384);  // 32KB quarter
        #pragma unroll
        for (int i = 0; i < 8; ++i)
            Bs[i * 256 + t] = gsrc[i * 256 + t];
        __syncthreads();
        const short8* B8 = (const short8*)Bs + l;
        #pragma unroll
        for (int nt = 0; nt < 16; ++nt) {
            short8 bf = B8[nt * 64];
            acc[nt] = __builtin_amdgcn_mfma_f32_16x16x32_bf16(af0, bf, acc[nt], 0, 0, 0);
        }
        B8 = (const short8*)Bs + (1024 + l);
        #pragma unroll
        for (int nt = 0; nt < 16; ++nt) {
            short8 bf = B8[nt * 64];
            acc[nt] = __builtin_amdgcn_mfma_f32_16x16x32_bf16(af1, bf, acc[nt], 0, 0, 0);
        }
    }

    // epilogue: D lane l reg e = H[row=(l>>4)*4+e][col=nt*16+(l&15)]
    float pl[4][3] = {{0.f}}, pr[4][3] = {{0.f}};
    #pragma unroll
    for (int nt = 0; nt < 16; ++nt) {
        int col = nt * 16 + (l & 15);
        float b = bls[col];
        #pragma unroll
        for (int e = 0; e < 4; ++e) {
            float h = fmaxf(acc[nt][e] + b, 0.0f);
            #pragma unroll
            for (int j = 0; j < 3; ++j) {
                pl[e][j] = fmaf(h, wl1s[col][j], pl[e][j]);
                pr[e][j] = fmaf(h, wr1s[col][j], pr[e][j]);
            }
        }
    }
    #pragma unroll
    for (int m = 1; m <= 8; m <<= 1) {
        #pragma unroll
        for (int e = 0; e < 4; ++e)
            #pragma unroll
            for (int j = 0; j < 3; ++j) {
                pl[e][j] += __shfl_xor(pl[e][j], m);
                pr[e][j] += __shfl_xor(pr[e][j], m);
            }
    }
    if ((l & 15) == 0) {
        #pragma unroll
        for (int e = 0; e < 4; ++e) {
            int node = n0 + (l >> 4) * 4 + e;
            if (node < NN) {
                #pragma unroll
                for (int j = 0; j < 3; ++j) {
                    g[node * 3 + j] = pl[e][j];
                    r[node * 3 + j] = pr[e][j];
                }
            }
        }
    }
}

// ---------------- kernel 5: layer-1 gather + final output ----------------
__global__ __launch_bounds__(256) void k_out(const int* __restrict__ degi,
                                             const unsigned short* __restrict__ csrp,
                                             const float* __restrict__ g,
                                             const float* __restrict__ r,
                                             const float* __restrict__ bl1,
                                             float* __restrict__ out) {
    int tid = blockIdx.x * 256 + threadIdx.x;
    int n = tid >> 3;
    int sl = tid & 7;
    if (n >= NN) return;
    int deg = min(degi[n << 4], PAD);
    int beg = n * PAD;
    float s0 = 0.f, s1 = 0.f, s2 = 0.f;
    for (int j = sl; j < deg; j += 8) {
        int src = csrp[beg + j];
        s0 += g[src * 3 + 0];
        s1 += g[src * 3 + 1];
        s2 += g[src * 3 + 2];
    }
    #pragma unroll
    for (int m = 1; m < 8; m <<= 1) {
        s0 += __shfl_xor(s0, m);
        s1 += __shfl_xor(s1, m);
        s2 += __shfl_xor(s2, m);
    }
    if (sl == 0) {
        float inv = 1.0f / fmaxf((float)deg, 1.0f);
        out[n * 3 + 0] = s0 * inv + bl1[0] + r[n * 3 + 0];
        out[n * 3 + 1] = s1 * inv + bl1[1] + r[n * 3 + 1];
        out[n * 3 + 2] = s2 * inv + bl1[2] + r[n * 3 + 2];
    }
}

extern "C" void kernel_launch(void* const* d_in, const int* in_sizes, int n_in,
                              void* d_out, int out_size, void* d_ws, size_t ws_size,
                              hipStream_t stream) {
    const float* x   = (const float*)d_in[0];
    const int*   ei  = (const int*)d_in[1];
    const float* Wl0 = (const float*)d_in[2];
    const float* bl0 = (const float*)d_in[3];
    const float* Wr0 = (const float*)d_in[4];
    const float* Wl1 = (const float*)d_in[5];
    const float* bl1 = (const float*)d_in[6];
    const float* Wr1 = (const float*)d_in[7];
    float* out = (float*)d_out;

    char* ws = (char*)d_ws;
    int*            degi = (int*)(ws);                        //  3,200,064 (NN*16 ints, 1 counter / 64B line)
    unsigned short* csrp = (unsigned short*)(ws + 3200064);   //  6,400,000 (NN*PAD*2)
    unsigned short* Ab   = (unsigned short*)(ws + 9600064);   // 25,624,576 (NNP*256*2)
    unsigned short* Bp   = (unsigned short*)(ws + 35224640);  //    131,072
    float*          g    = (float*)(ws + 35355712);           //    600,064
    float*          r    = (float*)(ws + 35955776);           //    600,064  -> ~36.6 MB

    k_zero <<<(NN * 4 + 255) / 256, 256, 0, stream>>>(degi);
    k_bprep<<<BP_BLOCKS, 256, 0, stream>>>(ei, x, Wl0, Wr0, degi, csrp, Ab, Bp);
    k_agg  <<<(NN * 64 + 255) / 256, 256, 0, stream>>>(degi, csrp, Ab);
    k_gemm <<<(NN + 63) / 64, 256, 0, stream>>>(Ab, Bp, bl0, Wl1, Wr1, g, r);
    k_out  <<<(NN * 8 + 255) / 256, 256, 0, stream>>>(degi, csrp, g, r, bl1, out);
}

// Round 21
// 104.942 us; speedup vs baseline: 1.3675x; 1.0313x over previous
//
#include <hip/hip_runtime.h>

#define NN 50000
#define NNP 50048   // Ab rows padded to multiple of 64
#define NE 640000
#define IC 128
#define HC 256
#define OC 3
#define PAD 64      // padded CSR row capacity; P(deg>=64)~1e-25 for Poisson(12.8); guarded anyway

#define TOBF16_BLOCKS (NN * IC / 4 / 256)          // 6250
#define WPACK_BLOCKS  32
#define DEGZ_BLOCKS   ((NN * 16 / 4 + 255) / 256)  // 782: zero NN*16 ints as uint4

typedef __attribute__((ext_vector_type(8))) short short8;
typedef __attribute__((ext_vector_type(4))) float f32x4;

__device__ __forceinline__ unsigned short f2bf(float f) {   // fp32 -> bf16 RNE
    unsigned int u = __float_as_uint(f);
    unsigned int r = u + 0x7FFFu + ((u >> 16) & 1u);
    return (unsigned short)(r >> 16);
}
__device__ __forceinline__ float bflo(unsigned int v) { return __uint_as_float(v << 16); }
__device__ __forceinline__ float bfhi(unsigned int v) { return __uint_as_float(v & 0xffff0000u); }

// ---------------- prep: zero spread-degi | x->bf16 | pack W ----------------
__global__ __launch_bounds__(256) void k_prep(const float* __restrict__ x,
                                              const float* __restrict__ Wl0,
                                              const float* __restrict__ Wr0,
                                              unsigned short* __restrict__ Ab,
                                              unsigned short* __restrict__ Bp,
                                              int* __restrict__ degi) {
    int b = blockIdx.x;
    int t = threadIdx.x;
    if (b < TOBF16_BLOCKS) {
        // x -> bf16 into right half of Ab (Ab: ushort[NNP][256], cols 128..255 = x)
        int i = b * 256 + t;                  // over NN*IC/4 float4s
        int n = i >> 5;
        int c = (i & 31) * 4;
        float4 v = ((const float4*)x)[i];
        ushort4 o;
        o.x = f2bf(v.x); o.y = f2bf(v.y); o.z = f2bf(v.z); o.w = f2bf(v.w);
        *(ushort4*)&Ab[(size_t)n * 256 + 128 + c] = o;
    } else if (b < TOBF16_BLOCKS + WPACK_BLOCKS) {
        // pack [Wl0;Wr0] into MFMA B-fragment order:
        // Bp[kt(8)][nt(16)][lane(64)][e(8)], B[k][n]: k=kt*32+(lane>>4)*8+e, n=nt*16+(lane&15)
        int tt = (b - TOBF16_BLOCKS) * 256 + t;     // 8192 threads
        int l = tt & 63;
        int nt = (tt >> 6) & 15;
        int kt = tt >> 10;
        int n = nt * 16 + (l & 15);
        int kbase = kt * 32 + (l >> 4) * 8;
        unsigned short o[8];
        #pragma unroll
        for (int e = 0; e < 8; ++e) {
            int k = kbase + e;
            float w = (k < IC) ? Wl0[k * HC + n] : Wr0[(k - IC) * HC + n];
            o[e] = f2bf(w);
        }
        #pragma unroll
        for (int e = 0; e < 8; ++e) Bp[(size_t)tt * 8 + e] = o[e];
    } else {
        // zero spread degi: counter n lives at degi[n*16] (one per 64B line)
        int idx = (b - TOBF16_BLOCKS - WPACK_BLOCKS) * 256 + t;
        if (idx < NN * 16 / 4) ((uint4*)degi)[idx] = make_uint4(0u, 0u, 0u, 0u);
    }
}

// ---------------- one-pass padded-CSR build; line-isolated counters ----------------
__global__ __launch_bounds__(256) void k_build(const int* __restrict__ ei,
                                               int* __restrict__ degi,
                                               unsigned short* __restrict__ csrp) {
    int e = blockIdx.x * blockDim.x + threadIdx.x;
    if (e >= NE) return;
    int src = ei[e];
    int dst = ei[NE + e];
    int rank = atomicAdd(&degi[dst << 4], 1);   // stride-16: one counter per cache line
    if (rank < PAD) csrp[dst * PAD + rank] = (unsigned short)src;
}

// ---------------- gather-mean: 8 edge-subgroups x 8 lanes x 2 uint4 (32B/lane) ----------------
__global__ __launch_bounds__(256) void k_agg(const int* __restrict__ degi,
                                             const unsigned short* __restrict__ csrp,
                                             unsigned short* __restrict__ Ab) {
    int wid = (blockIdx.x * blockDim.x + threadIdx.x) >> 6;
    int lane = threadIdx.x & 63;
    if (wid >= NN) return;
    int deg = min(degi[wid << 4], PAD);
    int beg = wid * PAD;
    int sg = lane >> 3;        // edge subgroup 0..7 (8 edges in flight per wave)
    int s  = lane & 7;         // this lane covers uint4 slots s and s+8 of the x-half
    const uint4* base = (const uint4*)Ab;     // 32 uint4 per 512B row

    float a[16];
    #pragma unroll
    for (int i = 0; i < 16; ++i) a[i] = 0.f;

    for (int j = sg; j < deg; j += 8) {
        int src = csrp[beg + j];
        uint4 v0 = base[(size_t)src * 32 + 16 + s];
        uint4 v1 = base[(size_t)src * 32 + 24 + s];
        a[0] += bflo(v0.x); a[1] += bfhi(v0.x);
        a[2] += bflo(v0.y); a[3] += bfhi(v0.y);
        a[4] += bflo(v0.z); a[5] += bfhi(v0.z);
        a[6] += bflo(v0.w); a[7] += bfhi(v0.w);
        a[8]  += bflo(v1.x); a[9]  += bfhi(v1.x);
        a[10] += bflo(v1.y); a[11] += bfhi(v1.y);
        a[12] += bflo(v1.z); a[13] += bfhi(v1.z);
        a[14] += bflo(v1.w); a[15] += bfhi(v1.w);
    }
    #pragma unroll
    for (int m = 8; m <= 32; m <<= 1)
        #pragma unroll
        for (int i = 0; i < 16; ++i) a[i] += __shfl_xor(a[i], m);

    if (sg == 0) {
        float inv = 1.0f / fmaxf((float)deg, 1.0f);
        uint4 o0, o1;
        o0.x = ((unsigned int)f2bf(a[1] * inv) << 16) | f2bf(a[0] * inv);
        o0.y = ((unsigned int)f2bf(a[3] * inv) << 16) | f2bf(a[2] * inv);
        o0.z = ((unsigned int)f2bf(a[5] * inv) << 16) | f2bf(a[4] * inv);
        o0.w = ((unsigned int)f2bf(a[7] * inv) << 16) | f2bf(a[6] * inv);
        o1.x = ((unsigned int)f2bf(a[9]  * inv) << 16) | f2bf(a[8]  * inv);
        o1.y = ((unsigned int)f2bf(a[11] * inv) << 16) | f2bf(a[10] * inv);
        o1.z = ((unsigned int)f2bf(a[13] * inv) << 16) | f2bf(a[12] * inv);
        o1.w = ((unsigned int)f2bf(a[15] * inv) << 16) | f2bf(a[14] * inv);
        ((uint4*)Ab)[(size_t)wid * 32 + s] = o0;
        ((uint4*)Ab)[(size_t)wid * 32 + 8 + s] = o1;
    }
}

// ---------------- MFMA GEMM v5: VGPR-capped for 4 waves/SIMD ----------------
// 16 rows/wave, 64 rows/block, 782 blocks. Per-quarter A loads (2 frags) issued
// before the staging barriers so their latency hides under stage+barrier.
// H = relu(Ab @ [Wl0;Wr0] + bl0); g = H@Wl1; r = H@Wr1
__global__ __launch_bounds__(256, 4) void k_gemm(const unsigned short* __restrict__ Ab,
                                                 const unsigned short* __restrict__ Bp,
                                                 const float* __restrict__ bl0,
                                                 const float* __restrict__ Wl1,
                                                 const float* __restrict__ Wr1,
                                                 float* __restrict__ g,
                                                 float* __restrict__ r) {
    __shared__ float4 Bs[2048];          // 32 KB: one K-quarter of packed B
    __shared__ float wl1s[HC][3];
    __shared__ float wr1s[HC][3];
    __shared__ float bls[HC];

    int t = threadIdx.x;
    for (int i = t; i < HC * 3; i += 256) {
        wl1s[i / 3][i % 3] = Wl1[i];
        wr1s[i / 3][i % 3] = Wr1[i];
    }
    for (int i = t; i < HC; i += 256) bls[i] = bl0[i];

    int w = t >> 6, l = t & 63;
    int n0 = blockIdx.x * 64 + w * 16;

    f32x4 acc[16];
    #pragma unroll
    for (int i = 0; i < 16; ++i) acc[i] = (f32x4){0.f, 0.f, 0.f, 0.f};

    // A-frag: lane l supplies A[n0 + (l&15)][kt*32 + (l>>4)*8 + e]
    const short8* A8 = (const short8*)Ab + ((size_t)(n0 + (l & 15)) * 32 + (l >> 4));

    for (int q = 0; q < 4; ++q) {
        // issue this quarter's two A fragments first: latency hides under stage+barrier
        short8 af0 = A8[(q * 2 + 0) * 4];
        short8 af1 = A8[(q * 2 + 1) * 4];
        __syncthreads();
        const float4* gsrc = (const float4*)(Bp + (size_t)q * 16384);  // 32KB quarter
        #pragma unroll
        for (int i = 0; i < 8; ++i)
            Bs[i * 256 + t] = gsrc[i * 256 + t];
        __syncthreads();
        const short8* B8 = (const short8*)Bs + l;
        #pragma unroll
        for (int nt = 0; nt < 16; ++nt) {
            short8 bf = B8[nt * 64];
            acc[nt] = __builtin_amdgcn_mfma_f32_16x16x32_bf16(af0, bf, acc[nt], 0, 0, 0);
        }
        B8 = (const short8*)Bs + (1024 + l);
        #pragma unroll
        for (int nt = 0; nt < 16; ++nt) {
            short8 bf = B8[nt * 64];
            acc[nt] = __builtin_amdgcn_mfma_f32_16x16x32_bf16(af1, bf, acc[nt], 0, 0, 0);
        }
    }

    // epilogue: D lane l reg e = H[row=(l>>4)*4+e][col=nt*16+(l&15)]
    float pl[4][3] = {{0.f}}, pr[4][3] = {{0.f}};
    #pragma unroll
    for (int nt = 0; nt < 16; ++nt) {
        int col = nt * 16 + (l & 15);
        float b = bls[col];
        #pragma unroll
        for (int e = 0; e < 4; ++e) {
            float h = fmaxf(acc[nt][e] + b, 0.0f);
            #pragma unroll
            for (int j = 0; j < 3; ++j) {
                pl[e][j] = fmaf(h, wl1s[col][j], pl[e][j]);
                pr[e][j] = fmaf(h, wr1s[col][j], pr[e][j]);
            }
        }
    }
    #pragma unroll
    for (int m = 1; m <= 8; m <<= 1) {
        #pragma unroll
        for (int e = 0; e < 4; ++e)
            #pragma unroll
            for (int j = 0; j < 3; ++j) {
                pl[e][j] += __shfl_xor(pl[e][j], m);
                pr[e][j] += __shfl_xor(pr[e][j], m);
            }
    }
    if ((l & 15) == 0) {
        #pragma unroll
        for (int e = 0; e < 4; ++e) {
            int node = n0 + (l >> 4) * 4 + e;
            if (node < NN) {
                #pragma unroll
                for (int j = 0; j < 3; ++j) {
                    g[node * 3 + j] = pl[e][j];
                    r[node * 3 + j] = pr[e][j];
                }
            }
        }
    }
}

// ---------------- fused layer-1 aggregation by GATHER + final output ----------------
__global__ __launch_bounds__(256) void k_out(const int* __restrict__ degi,
                                             const unsigned short* __restrict__ csrp,
                                             const float* __restrict__ g,
                                             const float* __restrict__ r,
                                             const float* __restrict__ bl1,
                                             float* __restrict__ out) {
    int tid = blockIdx.x * 256 + threadIdx.x;
    int n = tid >> 3;
    int sl = tid & 7;
    if (n >= NN) return;
    int deg = min(degi[n << 4], PAD);
    int beg = n * PAD;
    float s0 = 0.f, s1 = 0.f, s2 = 0.f;
    for (int j = sl; j < deg; j += 8) {
        int src = csrp[beg + j];
        s0 += g[src * 3 + 0];
        s1 += g[src * 3 + 1];
        s2 += g[src * 3 + 2];
    }
    #pragma unroll
    for (int m = 1; m < 8; m <<= 1) {
        s0 += __shfl_xor(s0, m);
        s1 += __shfl_xor(s1, m);
        s2 += __shfl_xor(s2, m);
    }
    if (sl == 0) {
        float inv = 1.0f / fmaxf((float)deg, 1.0f);
        out[n * 3 + 0] = s0 * inv + bl1[0] + r[n * 3 + 0];
        out[n * 3 + 1] = s1 * inv + bl1[1] + r[n * 3 + 1];
        out[n * 3 + 2] = s2 * inv + bl1[2] + r[n * 3 + 2];
    }
}

extern "C" void kernel_launch(void* const* d_in, const int* in_sizes, int n_in,
                              void* d_out, int out_size, void* d_ws, size_t ws_size,
                              hipStream_t stream) {
    const float* x   = (const float*)d_in[0];
    const int*   ei  = (const int*)d_in[1];
    const float* Wl0 = (const float*)d_in[2];
    const float* bl0 = (const float*)d_in[3];
    const float* Wr0 = (const float*)d_in[4];
    const float* Wl1 = (const float*)d_in[5];
    const float* bl1 = (const float*)d_in[6];
    const float* Wr1 = (const float*)d_in[7];
    float* out = (float*)d_out;

    char* ws = (char*)d_ws;
    int*            degi = (int*)(ws);                        //  3,200,064 (NN*16 ints, 1 counter / 64B line)
    unsigned short* csrp = (unsigned short*)(ws + 3200064);   //  6,400,000 (NN*PAD*2)
    unsigned short* Ab   = (unsigned short*)(ws + 9600064);   // 25,624,576 (NNP*256*2)
    unsigned short* Bp   = (unsigned short*)(ws + 35224640);  //    131,072
    float*          g    = (float*)(ws + 35355712);           //    600,064
    float*          r    = (float*)(ws + 35955776);           //    600,064  -> ~36.6 MB

    k_prep <<<TOBF16_BLOCKS + WPACK_BLOCKS + DEGZ_BLOCKS, 256, 0, stream>>>(x, Wl0, Wr0, Ab, Bp, degi);
    k_build<<<(NE + 255) / 256, 256, 0, stream>>>(ei, degi, csrp);
    k_agg  <<<(NN * 64 + 255) / 256, 256, 0, stream>>>(degi, csrp, Ab);
    k_gemm <<<(NN + 63) / 64, 256, 0, stream>>>(Ab, Bp, bl0, Wl1, Wr1, g, r);
    k_out  <<<(NN * 8 + 255) / 256, 256, 0, stream>>>(degi, csrp, g, r, bl1, out);
}